// Round 16
// baseline (168.074 us; speedup 1.0000x reference)
//
#include <hip/hip_runtime.h>

// NormEMAVectorQuantizer on MI355X (gfx950)
// N=8192 tokens, C=32, K=8192 codes, B=32, H*W=256.
// R16 = R15's 4-launch block-local pipeline with k_argmax rebuilt for B-reuse:
// R15 streamed B register-direct from L2 with 16 tok/block (zero reuse,
// 512MB L2->VGPR at ~200cyc latency -> 65us). Now: 32 tokens/block x ALL
// codes, 256 blocks (1/CU); B staged to LDS in 16KB chunks, DOUBLE-BUFFERED
// (stage ch+1 while computing ch); waves take tile-strided quarters of each
// chunk so one cooperative stage serves all 4 waves; 2 A-frags/wave.
// Traffic 512->256MB and on the LDS path (ds_read ~12cyc, latency hidden).
// Certificate: bf16 dot err <= 2*2^-9 = 0.0078 < eps=0.01 for unit rows ->
// every possible fp32 argmax (incl. ties) is exact-rescored in fp32;
// (8191-code) key = numpy lowest-index tie-break.
// Pipeline: prep+zero | argmax(+zq+loss) | scanplace | update.
//
// Outputs (float32, concatenated):
//   [0 .. 262144)        z_q_out [B,C,H,W]
//   [262144]             loss (scalar)
//   [262145 .. 270337)   token_ids [B,H,W] as float
//   [270337 .. 532481)   new_embedding [K,C]
//   [532481 .. 540673)   new_cluster_sizes [K]

#define NTOK   8192
#define NCODE  8192
#define CDIM   32
#define HW     256
#define DECAYF 0.99f
#define EPSF   0.01f

#define OUT_ZQ   0
#define OUT_LOSS 262144
#define OUT_IDS  262145
#define OUT_EMB  270337
#define OUT_CS   532481

// workspace byte offsets
#define WS_ZN     0u        // zn row-major [N,C] f32   = 1048576
#define WS_ZNBF   1048576u  // bf16 [N,C]               = 524288
#define WS_EBF    1572864u  // bf16 [K,C]               = 524288
#define WS_BINS   2097152u  // i32 [K]                  = 32768
#define WS_LOSSP  2129920u  // f32 [64]                 = 256
#define WS_IDS    2130176u  // i32 [N]
#define WS_POS    2162944u  // i32 [N]
#define WS_OFFS   2195712u  // i32 [K]
#define WS_SORTED 2228480u  // i32 [N]   (end 2261248)

#define CHUNK  256          // codes per staged LDS chunk
#define NCHUNK (NCODE / CHUNK)  // 32

typedef __attribute__((ext_vector_type(8))) short bf16x8;
typedef __attribute__((ext_vector_type(4))) float f32x4;

__device__ inline unsigned short f2bf(float x) {
    unsigned u = __float_as_uint(x);
    return (unsigned short)((u + 0x7FFFu + ((u >> 16) & 1u)) >> 16);
}
__device__ inline unsigned fmap(float s) {   // monotonic f32 -> u32
    unsigned u = __float_as_uint(s);
    return (u & 0x80000000u) ? ~u : (u | 0x80000000u);
}

// -------- Kernel A: prep (norm + bf16) + zero bins/loss_part -------------------
__global__ __launch_bounds__(256) void k_prep(const float* __restrict__ z,
                                              const float* __restrict__ emb,
                                              float* __restrict__ zn,
                                              unsigned short* __restrict__ znbf,
                                              unsigned short* __restrict__ ebf,
                                              int* __restrict__ bins,
                                              float* __restrict__ loss_part) {
    int bid = blockIdx.x, t = threadIdx.x;
    if (bid < 32) {                               // token norm -> zn, znbf
        int n = bid * 256 + t;
        int b = n >> 8, hw = n & 255;
        const float* zp = z + (size_t)b * (CDIM * HW) + hw;
        float v[CDIM];
        float ss = 0.f;
#pragma unroll
        for (int c = 0; c < CDIM; ++c) {
            float tv = zp[c * HW];                // coalesced per c
            v[c] = tv;
            ss += tv * tv;
        }
        float d = fmaxf(sqrtf(ss), 1e-12f);
        float* o = zn + (size_t)n * CDIM;
        unsigned short* ob = znbf + (size_t)n * CDIM;
#pragma unroll
        for (int c = 0; c < CDIM; ++c) {
            float tv = v[c] / d;
            o[c] = tv;
            ob[c] = f2bf(tv);
        }
    } else if (bid < 160) {                       // emb -> ebf
        int base = (bid - 32) * 2048 + t * 8;
        const float4* s = (const float4*)(emb + base);
        float4 x4 = s[0], y4 = s[1];
        ushort4 u0 = {f2bf(x4.x), f2bf(x4.y), f2bf(x4.z), f2bf(x4.w)};
        ushort4 u1 = {f2bf(y4.x), f2bf(y4.y), f2bf(y4.z), f2bf(y4.w)};
        *(ushort4*)(ebf + base) = u0;
        *(ushort4*)(ebf + base + 4) = u1;
    } else if (bid < 164) {                       // zero bins
        int base = (bid - 160) * 2048 + t;
#pragma unroll
        for (int j = 0; j < 8; ++j) bins[base + j * 256] = 0;
    } else {                                      // bid==164: zero loss_part
        if (t < 64) loss_part[t] = 0.f;
    }
}

// -------- Kernel B: block-local argmax, LDS-staged dbuf B, + z_q + loss --------
// 256 blocks x 256 thr. Block owns 32 tokens (2 A-frags/wave); 32 chunks of
// 256 codes staged to LDS; wave w computes tiles {w, w+4, w+8, w+12} of each.
__global__ __launch_bounds__(256) void k_argmax(const unsigned short* __restrict__ znbf,
                                                const unsigned short* __restrict__ ebf,
                                                const float* __restrict__ zn,
                                                const float* __restrict__ emb,
                                                int* __restrict__ bins,
                                                int* __restrict__ ids,
                                                int* __restrict__ pos,
                                                float* __restrict__ out,
                                                float* __restrict__ loss_part) {
    __shared__ unsigned short lbs[2][CHUNK * CDIM];  // 2 x 16 KiB
    __shared__ float gm[4][32];
    __shared__ float thr[32];
    __shared__ unsigned long long bk[32];
    __shared__ int sid[32];
    __shared__ float ls4[4];

    int blk = blockIdx.x, t = threadIdx.x;
    int wave = t >> 6, lane = t & 63;
    int col = lane & 15, quad = lane >> 4;
    int tok0 = blk * 32;

    // A-frags: block's 32 tokens, 2 frags (same for all waves)
    bf16x8 a[2];
#pragma unroll
    for (int f = 0; f < 2; ++f)
        a[f] = *(const bf16x8*)(znbf + (size_t)(tok0 + f * 16 + col) * CDIM + quad * 8);

    const f32x4 zero4 = {0.f, 0.f, 0.f, 0.f};
    const float4* esrc = (const float4*)ebf;      // 16B units; chunk = 1024 units

    // stage chunk 0
    {
        float4* dst = (float4*)lbs[0];
#pragma unroll
        for (int j = 0; j < 4; ++j) dst[t + j * 256] = esrc[t + j * 256];
    }
    __syncthreads();

    // ---- pass 1: running max, double-buffered chunks ----
    float m[2][4];
#pragma unroll
    for (int f = 0; f < 2; ++f)
#pragma unroll
        for (int r = 0; r < 4; ++r) m[f][r] = -1e30f;

    for (int ch = 0; ch < NCHUNK; ++ch) {
        int buf = ch & 1;
        if (ch + 1 < NCHUNK) {                    // stage next while computing
            float4* dst = (float4*)lbs[buf ^ 1];
            const float4* src = esrc + (size_t)(ch + 1) * 1024;
#pragma unroll
            for (int j = 0; j < 4; ++j) dst[t + j * 256] = src[t + j * 256];
        }
        const bf16x8* bl = (const bf16x8*)lbs[buf];
#pragma unroll
        for (int i = 0; i < 4; ++i) {             // tiles wave, wave+4, +8, +12
            int tile = wave + i * 4;
            bf16x8 b = bl[(tile * 16 + col) * 4 + quad];
#pragma unroll
            for (int f = 0; f < 2; ++f) {
                f32x4 d = __builtin_amdgcn_mfma_f32_16x16x32_bf16(a[f], b, zero4, 0, 0, 0);
#pragma unroll
                for (int r = 0; r < 4; ++r) m[f][r] = fmaxf(m[f][r], d[r]);
            }
        }
        __syncthreads();                          // staged nxt ready; buf free
    }
    // cross-col reduce -> per-wave maxima for all 32 tokens
#pragma unroll
    for (int f = 0; f < 2; ++f)
#pragma unroll
        for (int r = 0; r < 4; ++r) {
            float v = m[f][r];
#pragma unroll
            for (int s = 1; s < 16; s <<= 1) v = fmaxf(v, __shfl_xor(v, s));
            if (col == 0) gm[wave][f * 16 + quad * 4 + r] = v;
        }
    if (t < 32) bk[t] = 0ull;
    __syncthreads();
    if (t < 32)
        thr[t] = fmaxf(fmaxf(gm[0][t], gm[1][t]), fmaxf(gm[2][t], gm[3][t])) - EPSF;
    __syncthreads();

    float th[2][4];
#pragma unroll
    for (int f = 0; f < 2; ++f)
#pragma unroll
        for (int r = 0; r < 4; ++r) th[f][r] = thr[f * 16 + quad * 4 + r];

    // ---- pass 2: rescan, qualify, exact fp32 rescore -> LDS key max ----
    {
        float4* dst = (float4*)lbs[0];
#pragma unroll
        for (int j = 0; j < 4; ++j) dst[t + j * 256] = esrc[t + j * 256];
    }
    __syncthreads();
    for (int ch = 0; ch < NCHUNK; ++ch) {
        int buf = ch & 1;
        if (ch + 1 < NCHUNK) {
            float4* dst = (float4*)lbs[buf ^ 1];
            const float4* src = esrc + (size_t)(ch + 1) * 1024;
#pragma unroll
            for (int j = 0; j < 4; ++j) dst[t + j * 256] = src[t + j * 256];
        }
        const bf16x8* bl = (const bf16x8*)lbs[buf];
#pragma unroll
        for (int i = 0; i < 4; ++i) {
            int tile = wave + i * 4;
            bf16x8 b = bl[(tile * 16 + col) * 4 + quad];
#pragma unroll
            for (int f = 0; f < 2; ++f) {
                f32x4 d = __builtin_amdgcn_mfma_f32_16x16x32_bf16(a[f], b, zero4, 0, 0, 0);
#pragma unroll
                for (int r = 0; r < 4; ++r) {
                    if (d[r] >= th[f][r]) {       // rare: ~1.05/token total
                        int tl = f * 16 + quad * 4 + r;
                        int code = ch * CHUNK + tile * 16 + col;
                        const float* zp = zn + (size_t)(tok0 + tl) * CDIM;
                        const float* ep = emb + (size_t)code * CDIM;
                        float a0 = 0.f, a1 = 0.f, a2 = 0.f, a3 = 0.f;
#pragma unroll
                        for (int j = 0; j < 8; ++j) {
                            a0 = __builtin_fmaf(zp[4 * j + 0], ep[4 * j + 0], a0);
                            a1 = __builtin_fmaf(zp[4 * j + 1], ep[4 * j + 1], a1);
                            a2 = __builtin_fmaf(zp[4 * j + 2], ep[4 * j + 2], a2);
                            a3 = __builtin_fmaf(zp[4 * j + 3], ep[4 * j + 3], a3);
                        }
                        float s = (a0 + a1) + (a2 + a3);
                        unsigned long long key =
                            ((unsigned long long)fmap(s) << 13) |
                            (unsigned long long)(8191 - code);
                        atomicMax(&bk[tl], key);  // LDS atomic, rare
                    }
                }
            }
        }
        __syncthreads();
    }

    // ---- epilogue: ids/pos ----
    if (t < 32) {
        int id = 8191 - (int)(bk[t] & 8191ull);
        sid[t] = id;
        int n = tok0 + t;
        ids[n] = id;
        out[OUT_IDS + n] = (float)id;
        pos[n] = atomicAdd(bins + id, 1);         // 8192 scattered atomics total
    }
    __syncthreads();

    // ---- z_q gather + transpose-out + loss ----
    float s = 0.f;
#pragma unroll
    for (int i = 0; i < 4; ++i) {
        int tl = i * 8 + (t >> 5);                // token-local 0..31
        int c = t & 31;
        int n = tok0 + tl;
        int id = sid[tl];
        float ev = emb[(size_t)id * CDIM + c];    // <=32 rows, L1-resident
        float zv = zn[(size_t)n * CDIM + c];      // coalesced row reads
        int b = n >> 8, hw = n & 255;
        out[OUT_ZQ + ((size_t)b * CDIM + c) * HW + hw] = ev;
        float dd = ev - zv;
        s += dd * dd;
    }
#pragma unroll
    for (int off = 32; off > 0; off >>= 1) s += __shfl_down(s, off);
    if (lane == 0) ls4[wave] = s;
    __syncthreads();
    if (t == 0)
        atomicAdd(loss_part + (blk & 63), ls4[0] + ls4[1] + ls4[2] + ls4[3]);
}

// -------- Kernel S: single-block scan of bins (wave-shuffle) + place sorted ----
__global__ __launch_bounds__(1024) void k_scanplace(const int* __restrict__ bins,
                                                    const int* __restrict__ ids,
                                                    const int* __restrict__ pos,
                                                    int* __restrict__ offs,
                                                    int* __restrict__ sorted) {
    __shared__ int wtot[16], wexcl[16];
    int t = threadIdx.x;
    int lane = t & 63, wid = t >> 6;
    int loc[8];
    int s = 0;
#pragma unroll
    for (int i = 0; i < 8; ++i) {                 // local exclusive prefix
        loc[i] = s;
        s += bins[t * 8 + i];
    }
    int v = s;                                    // wave-inclusive scan
#pragma unroll
    for (int sh = 1; sh < 64; sh <<= 1) {
        int o = __shfl_up(v, sh);
        if (lane >= sh) v += o;
    }
    if (lane == 63) wtot[wid] = v;
    __syncthreads();
    if (t < 16) {                                 // scan 16 wave totals
        int w = wtot[t];
        int iv = w;
#pragma unroll
        for (int sh = 1; sh < 16; sh <<= 1) {
            int o = __shfl_up(iv, sh);
            if (t >= sh) iv += o;
        }
        wexcl[t] = iv - w;
    }
    __syncthreads();
    int excl = wexcl[wid] + (v - s);              // global exclusive for thread
#pragma unroll
    for (int i = 0; i < 8; ++i) offs[t * 8 + i] = excl + loc[i];
    __syncthreads();
    for (int n = t; n < NTOK; n += 1024)
        sorted[offs[ids[n]] + pos[n]] = n;
}

// -------- Kernel F: EMA update via segment gather + renormalize + loss ---------
__global__ __launch_bounds__(256) void k_update(const float* __restrict__ zn,
                                                const float* __restrict__ emb,
                                                const float* __restrict__ cs,
                                                const int* __restrict__ bins,
                                                const int* __restrict__ offs,
                                                const int* __restrict__ sorted,
                                                const float* __restrict__ loss_part,
                                                float* __restrict__ out) {
    int idx = blockIdx.x * 256 + threadIdx.x;
    if (blockIdx.x == 0 && threadIdx.x < 64) {    // loss finalize (wave 0)
        float lp = loss_part[threadIdx.x];
#pragma unroll
        for (int sh = 32; sh > 0; sh >>= 1) lp += __shfl_down(lp, sh);
        if (threadIdx.x == 0) out[OUT_LOSS] = lp * (1.0f / 262144.0f);
    }
    int k = idx >> 5, c = idx & 31;
    int bi = bins[k];
    int off = offs[k];
    float t = 0.f;
    for (int i = 0; i < bi; ++i) {                // avg 1 iter
        int n = sorted[off + i];
        t += zn[(size_t)n * CDIM + c];            // coalesced 128B row
    }
    float bf = (float)bi;
    bool zero = (bi == 0);
    t /= (zero ? 1.0f : bf);
    float ss = t * t;
#pragma unroll
    for (int s = 1; s < 32; s <<= 1) ss += __shfl_xor(ss, s);
    float d = fmaxf(sqrtf(ss), 1e-12f);
    float ew = emb[idx];
    float en = zero ? ew : (t / d);
    float w = ew * DECAYF + (1.0f - DECAYF) * en;
    float ss2 = w * w;
#pragma unroll
    for (int s = 1; s < 32; s <<= 1) ss2 += __shfl_xor(ss2, s);
    float d2 = fmaxf(sqrtf(ss2), 1e-12f);
    out[OUT_EMB + idx] = w / d2;
    if (c == 0) out[OUT_CS + k] = cs[k] * DECAYF + (1.0f - DECAYF) * bf;
}

extern "C" void kernel_launch(void* const* d_in, const int* in_sizes, int n_in,
                              void* d_out, int out_size, void* d_ws, size_t ws_size,
                              hipStream_t stream) {
    const float* z   = (const float*)d_in[0];   // [32,32,16,16]
    const float* emb = (const float*)d_in[1];   // [8192,32]
    const float* cs  = (const float*)d_in[2];   // [8192]
    float* out = (float*)d_out;
    char* ws = (char*)d_ws;

    float* zn            = (float*)(ws + WS_ZN);
    unsigned short* znbf = (unsigned short*)(ws + WS_ZNBF);
    unsigned short* ebf  = (unsigned short*)(ws + WS_EBF);
    int* bins            = (int*)(ws + WS_BINS);
    float* loss_part     = (float*)(ws + WS_LOSSP);
    int* ids             = (int*)(ws + WS_IDS);
    int* pos             = (int*)(ws + WS_POS);
    int* offs            = (int*)(ws + WS_OFFS);
    int* sorted          = (int*)(ws + WS_SORTED);

    k_prep<<<dim3(165), 256, 0, stream>>>(z, emb, zn, znbf, ebf, bins, loss_part);
    k_argmax<<<dim3(NTOK / 32), 256, 0, stream>>>(znbf, ebf, zn, emb, bins, ids,
                                                  pos, out, loss_part);
    k_scanplace<<<dim3(1), 1024, 0, stream>>>(bins, ids, pos, offs, sorted);
    k_update<<<dim3(1024), 256, 0, stream>>>(zn, emb, cs, bins, offs, sorted,
                                             loss_part, out);
}

// Round 17
// 119.807 us; speedup vs baseline: 1.4029x; 1.4029x over previous
//
#include <hip/hip_runtime.h>

// NormEMAVectorQuantizer on MI355X (gfx950)
// N=8192 tokens, C=32, K=8192 codes, B=32, H*W=256.
// R17 = R12's proven 1024-block dense two-sweep argmax (the only fast shape:
// 4 blocks/CU hides staging latency; R15/R16 block-local variants were
// latency-bound at 1-2 blocks/CU) with:
//  (a) LDS code rows padded 64B->80B: read/write bank conflicts 8-way -> 2-way
//      (free, m136). R12 counted 524K conflicts/sweep.
//  (b) 7 -> 4 dispatches: memset folded into k_prep; postzq+scanplace+update
//      replaced by ONE k_final (256 blocks): block b = ids/zq/loss for its 32
//      tokens + bins/esum (scan packed, LDS accumulate) + EMA for its 32
//      codes. Counting sort deleted. Loss via per-block atomicAdd into
//      out[LOSS] (zeroed by prep; fp32 order noise << threshold).
// Certificate: bf16 dot err <= 2*2^-9 = 0.0078 < eps=0.01 for unit rows ->
// every code that can be the fp32 argmax (incl. all ties) is exact-rescored
// in fp32; (8191-code) key = numpy lowest-index tie-break.
//
// Outputs (float32, concatenated):
//   [0 .. 262144)        z_q_out [B,C,H,W]
//   [262144]             loss (scalar)
//   [262145 .. 270337)   token_ids [B,H,W] as float
//   [270337 .. 532481)   new_embedding [K,C]
//   [532481 .. 540673)   new_cluster_sizes [K]

#define NTOK   8192
#define NCODE  8192
#define CDIM   32
#define HW     256
#define DECAYF 0.99f
#define EPSF   0.01f

#define OUT_ZQ   0
#define OUT_LOSS 262144
#define OUT_IDS  262145
#define OUT_EMB  270337
#define OUT_CS   532481

// workspace byte offsets
#define WS_ZN     0u        // zn row-major [N,C] f32   = 1048576
#define WS_ZNBF   1048576u  // bf16 [N,C]               = 524288
#define WS_EBF    1572864u  // bf16 [K,C]               = 524288
#define WS_PMAX   2097152u  // f32 [32][N]              = 1048576
#define WS_PACK   3145728u  // u64 [N]                  = 65536   (end 3211264)

#define CHUNK  256
#define NCHUNK (NCODE / CHUNK)  // 32
#define TILES  (CHUNK / 16)     // 16

typedef __attribute__((ext_vector_type(8))) short bf16x8;
typedef __attribute__((ext_vector_type(4))) float f32x4;

__device__ inline unsigned short f2bf(float x) {
    unsigned u = __float_as_uint(x);
    return (unsigned short)((u + 0x7FFFu + ((u >> 16) & 1u)) >> 16);
}
__device__ inline unsigned fmap(float s) {   // monotonic f32 -> u32
    unsigned u = __float_as_uint(s);
    return (u & 0x80000000u) ? ~u : (u | 0x80000000u);
}

// stage one 256x32 bf16 chunk into LDS with rows padded to 5 float4 units
// (80B): banks cycle 20*row%32 -> max 2-way conflict on read and write.
__device__ inline void stage_chunk(const unsigned short* __restrict__ ebf,
                                   int kbase, float4* lbs5, int t) {
    const float4* src = (const float4*)(ebf + (size_t)kbase * CDIM);
#pragma unroll
    for (int j = 0; j < 4; ++j) {
        int u = t + j * 256;                      // global float4 unit in chunk
        int row = u >> 2, seg = u & 3;
        lbs5[row * 5 + seg] = src[u];
    }
}

// -------- Kernel A: prep (norm + bf16 + emb bf16) + zero packed + zero loss ----
__global__ __launch_bounds__(256) void k_prep(const float* __restrict__ z,
                                              const float* __restrict__ emb,
                                              float* __restrict__ zn,
                                              unsigned short* __restrict__ znbf,
                                              unsigned short* __restrict__ ebf,
                                              unsigned long long* __restrict__ packed,
                                              float* __restrict__ out) {
    int bid = blockIdx.x, t = threadIdx.x;
    if (bid < 32) {                               // token norm -> zn, znbf
        int n = bid * 256 + t;
        int b = n >> 8, hw = n & 255;
        const float* zp = z + (size_t)b * (CDIM * HW) + hw;
        float v[CDIM];
        float ss = 0.f;
#pragma unroll
        for (int c = 0; c < CDIM; ++c) {
            float tv = zp[c * HW];                // coalesced per c
            v[c] = tv;
            ss += tv * tv;
        }
        float d = fmaxf(sqrtf(ss), 1e-12f);
        float* o = zn + (size_t)n * CDIM;
        unsigned short* ob = znbf + (size_t)n * CDIM;
#pragma unroll
        for (int c = 0; c < CDIM; ++c) {
            float tv = v[c] / d;
            o[c] = tv;
            ob[c] = f2bf(tv);
        }
    } else if (bid < 160) {                       // emb -> ebf
        int base = (bid - 32) * 2048 + t * 8;
        const float4* s = (const float4*)(emb + base);
        float4 x4 = s[0], y4 = s[1];
        ushort4 u0 = {f2bf(x4.x), f2bf(x4.y), f2bf(x4.z), f2bf(x4.w)};
        ushort4 u1 = {f2bf(y4.x), f2bf(y4.y), f2bf(y4.z), f2bf(y4.w)};
        *(ushort4*)(ebf + base) = u0;
        *(ushort4*)(ebf + base + 4) = u1;
    } else if (bid < 164) {                       // zero packed
        int base = (bid - 160) * 2048 + t;
#pragma unroll
        for (int j = 0; j < 8; ++j) packed[base + j * 256] = 0ull;
    } else {                                      // bid==164: zero loss slot
        if (t == 0) out[OUT_LOSS] = 0.f;
    }
}

// -------- Kernel B: MFMA sweep -> pmax[chunk][tok] (padded LDS, no conflicts) --
__global__ __launch_bounds__(256) void k_max(const unsigned short* __restrict__ znbf,
                                             const unsigned short* __restrict__ ebf,
                                             float* __restrict__ pmax) {
    __shared__ float4 lbs5[CHUNK * 5];            // 20 KiB, 80B rows
    __shared__ float lmax[256];
    int kbase = blockIdx.y * CHUNK;
    stage_chunk(ebf, kbase, lbs5, threadIdx.x);
    __syncthreads();

    int wave = threadIdx.x >> 6, lane = threadIdx.x & 63;
    int col = lane & 15, quad = lane >> 4;
    int wtok = blockIdx.x * 256 + wave * 64;

    bf16x8 a[4];                                  // 4 frags = 64 tokens
#pragma unroll
    for (int f = 0; f < 4; ++f)
        a[f] = *(const bf16x8*)(znbf + (size_t)(wtok + f * 16 + col) * CDIM + quad * 8);

    const bf16x8* bl = (const bf16x8*)lbs5;       // 16B units, row stride 5
    const f32x4 zero4 = {0.f, 0.f, 0.f, 0.f};
    float m[4][4];
#pragma unroll
    for (int f = 0; f < 4; ++f)
#pragma unroll
        for (int r = 0; r < 4; ++r) m[f][r] = -1e30f;

    for (int t = 0; t < TILES; ++t) {
        bf16x8 b = bl[(t * 16 + col) * 5 + quad];
#pragma unroll
        for (int f = 0; f < 4; ++f) {
            f32x4 d = __builtin_amdgcn_mfma_f32_16x16x32_bf16(a[f], b, zero4, 0, 0, 0);
#pragma unroll
            for (int r = 0; r < 4; ++r) m[f][r] = fmaxf(m[f][r], d[r]);
        }
    }
#pragma unroll
    for (int f = 0; f < 4; ++f)
#pragma unroll
        for (int r = 0; r < 4; ++r) {
            float v = m[f][r];
#pragma unroll
            for (int s = 1; s < 16; s <<= 1) v = fmaxf(v, __shfl_xor(v, s));
            if (col == 0) lmax[wave * 64 + f * 16 + quad * 4 + r] = v;
        }
    __syncthreads();
    pmax[(size_t)blockIdx.y * NTOK + blockIdx.x * 256 + threadIdx.x] = lmax[threadIdx.x];
}

// -------- Kernel C: dense rescan vs gmax-eps + inline exact fp32 rescore -------
__global__ __launch_bounds__(256) void k_pick(const unsigned short* __restrict__ znbf,
                                              const unsigned short* __restrict__ ebf,
                                              const float* __restrict__ zn,
                                              const float* __restrict__ emb,
                                              const float* __restrict__ pmax,
                                              unsigned long long* __restrict__ packed) {
    __shared__ float4 lbs5[CHUNK * 5];            // 20 KiB
    __shared__ float lthr[256];
    int kbase = blockIdx.y * CHUNK;
    stage_chunk(ebf, kbase, lbs5, threadIdx.x);
    {   // per-token global threshold: 32 coalesced loads
        int tok = blockIdx.x * 256 + threadIdx.x;
        float mx = -1e30f;
#pragma unroll
        for (int ch = 0; ch < NCHUNK; ++ch)
            mx = fmaxf(mx, pmax[(size_t)ch * NTOK + tok]);
        lthr[threadIdx.x] = mx - EPSF;
    }
    __syncthreads();

    int wave = threadIdx.x >> 6, lane = threadIdx.x & 63;
    int col = lane & 15, quad = lane >> 4;
    int wtok = blockIdx.x * 256 + wave * 64;

    bf16x8 a[4];
#pragma unroll
    for (int f = 0; f < 4; ++f)
        a[f] = *(const bf16x8*)(znbf + (size_t)(wtok + f * 16 + col) * CDIM + quad * 8);

    float thr[4][4];
#pragma unroll
    for (int f = 0; f < 4; ++f)
#pragma unroll
        for (int r = 0; r < 4; ++r)
            thr[f][r] = lthr[wave * 64 + f * 16 + quad * 4 + r];

    const bf16x8* bl = (const bf16x8*)lbs5;
    const f32x4 zero4 = {0.f, 0.f, 0.f, 0.f};

    for (int t = 0; t < TILES; ++t) {
        bf16x8 b = bl[(t * 16 + col) * 5 + quad];
#pragma unroll
        for (int f = 0; f < 4; ++f) {
            f32x4 d = __builtin_amdgcn_mfma_f32_16x16x32_bf16(a[f], b, zero4, 0, 0, 0);
#pragma unroll
            for (int r = 0; r < 4; ++r) {
                if (d[r] >= thr[f][r]) {          // rare: ~1.05/token total
                    int tok = wtok + f * 16 + quad * 4 + r;
                    int code = kbase + t * 16 + col;
                    const float* zp = zn + (size_t)tok * CDIM;
                    const float* ep = emb + (size_t)code * CDIM;
                    float a0 = 0.f, a1 = 0.f, a2 = 0.f, a3 = 0.f;
#pragma unroll
                    for (int j = 0; j < 8; ++j) {
                        a0 = __builtin_fmaf(zp[4 * j + 0], ep[4 * j + 0], a0);
                        a1 = __builtin_fmaf(zp[4 * j + 1], ep[4 * j + 1], a1);
                        a2 = __builtin_fmaf(zp[4 * j + 2], ep[4 * j + 2], a2);
                        a3 = __builtin_fmaf(zp[4 * j + 3], ep[4 * j + 3], a3);
                    }
                    float s = (a0 + a1) + (a2 + a3);
                    atomicMax(packed + tok, ((unsigned long long)fmap(s) << 13) |
                                            (unsigned long long)(8191 - code));
                }
            }
        }
    }
}

// -------- Kernel D: fused epilogue, 256 blocks ---------------------------------
// Block b: (a) ids/z_q/loss for tokens 32b..32b+31; (b) bins+esum for codes
// 32b..32b+31 by scanning all packed (coalesced, ~8 hits/wave), then EMA.
__global__ __launch_bounds__(256) void k_final(const unsigned long long* __restrict__ packed,
                                               const float* __restrict__ zn,
                                               const float* __restrict__ emb,
                                               const float* __restrict__ cs,
                                               float* __restrict__ out) {
    __shared__ float lesum[32][32];               // 4 KiB
    __shared__ int lbins[32];
    __shared__ int lsid[32];
    __shared__ float ls4[4];

    int blk = blockIdx.x, t = threadIdx.x;
    int wave = t >> 6, lane = t & 63;
    int tok0 = blk * 32, kbase = blk * 32;

    if (t < 32) lbins[t] = 0;
#pragma unroll
    for (int i = 0; i < 4; ++i) {
        int idx = i * 256 + t;
        lesum[idx >> 5][idx & 31] = 0.f;
    }
    if (t < 32) {                                 // unpack ids for our tokens
        int n = tok0 + t;
        int id = 8191 - (int)(packed[n] & 8191ull);
        lsid[t] = id;
        out[OUT_IDS + n] = (float)id;
    }
    __syncthreads();

    // ---- z_q gather + transpose-out + loss partial ----
    float s = 0.f;
#pragma unroll
    for (int i = 0; i < 4; ++i) {
        int idx = i * 256 + t;
        int tl = idx >> 5, c = idx & 31;
        int n = tok0 + tl;
        int id = lsid[tl];
        float ev = emb[(size_t)id * CDIM + c];    // <=32 rows, L1/L2
        float zv = zn[(size_t)n * CDIM + c];      // coalesced row reads
        int b = n >> 8, hw = n & 255;
        out[OUT_ZQ + ((size_t)b * CDIM + c) * HW + hw] = ev;
        float dd = ev - zv;
        s += dd * dd;
    }
#pragma unroll
    for (int off = 32; off > 0; off >>= 1) s += __shfl_down(s, off);
    if (lane == 0) ls4[wave] = s;
    __syncthreads();
    if (t == 0)
        atomicAdd(out + OUT_LOSS,
                  (ls4[0] + ls4[1] + ls4[2] + ls4[3]) * (1.0f / 262144.0f));

    // ---- bins + esum: scan all tokens for hits in our code window ----
    for (int i = 0; i < 32; ++i) {
        int n = i * 256 + t;                      // coalesced
        int id = 8191 - (int)(packed[n] & 8191ull);
        unsigned kl = (unsigned)(id - kbase);
        if (kl < 32u) {                           // ~8 hits per wave total
            atomicAdd(&lbins[kl], 1);
            const float* zp = zn + (size_t)n * CDIM;
#pragma unroll
            for (int c = 0; c < CDIM; ++c)
                atomicAdd(&lesum[kl][c], zp[c]);
        }
    }
    __syncthreads();

    // ---- EMA update + renormalize for our 32 codes ----
#pragma unroll
    for (int i = 0; i < 4; ++i) {
        int idx = i * 256 + t;
        int kl = idx >> 5, c = idx & 31;
        int k = kbase + kl;
        int bi = lbins[kl];
        float bf = (float)bi;
        bool zero = (bi == 0);
        float tv = lesum[kl][c] / (zero ? 1.0f : bf);
        float ss = tv * tv;
#pragma unroll
        for (int sh = 1; sh < 32; sh <<= 1) ss += __shfl_xor(ss, sh);
        float d = fmaxf(sqrtf(ss), 1e-12f);
        float ew = emb[(size_t)k * CDIM + c];
        float en = zero ? ew : (tv / d);
        float w = ew * DECAYF + (1.0f - DECAYF) * en;
        float ss2 = w * w;
#pragma unroll
        for (int sh = 1; sh < 32; sh <<= 1) ss2 += __shfl_xor(ss2, sh);
        float d2 = fmaxf(sqrtf(ss2), 1e-12f);
        out[OUT_EMB + (size_t)k * CDIM + c] = w / d2;
        if (c == 0) out[OUT_CS + k] = cs[k] * DECAYF + (1.0f - DECAYF) * bf;
    }
}

extern "C" void kernel_launch(void* const* d_in, const int* in_sizes, int n_in,
                              void* d_out, int out_size, void* d_ws, size_t ws_size,
                              hipStream_t stream) {
    const float* z   = (const float*)d_in[0];   // [32,32,16,16]
    const float* emb = (const float*)d_in[1];   // [8192,32]
    const float* cs  = (const float*)d_in[2];   // [8192]
    float* out = (float*)d_out;
    char* ws = (char*)d_ws;

    float* zn                  = (float*)(ws + WS_ZN);
    unsigned short* znbf       = (unsigned short*)(ws + WS_ZNBF);
    unsigned short* ebf        = (unsigned short*)(ws + WS_EBF);
    float* pmax                = (float*)(ws + WS_PMAX);
    unsigned long long* packed = (unsigned long long*)(ws + WS_PACK);

    k_prep<<<dim3(165), 256, 0, stream>>>(z, emb, zn, znbf, ebf, packed, out);
    k_max<<<dim3(NTOK / 256, NCHUNK), 256, 0, stream>>>(znbf, ebf, pmax);
    k_pick<<<dim3(NTOK / 256, NCHUNK), 256, 0, stream>>>(znbf, ebf, zn, emb, pmax, packed);
    k_final<<<dim3(256), 256, 0, stream>>>(packed, zn, emb, cs, out);
}